// Round 3
// baseline (595.484 us; speedup 1.0000x reference)
//
#include <hip/hip_runtime.h>
#include <hip/hip_bf16.h>

// Match numpy: no FMA contraction anywhere that feeds the Jacobi argmax.
#pragma clang fp contract(off)

#define N 4096
#define CIN 64
#define COUT 64
#define RR 4
#define ITERS 10

// Fused: deg[i] += 1 for row array, A[row,col] += 1 (exact small ints in f32)
__global__ void edges_k(const int* __restrict__ ei, float* __restrict__ deg,
                        float* __restrict__ a, int E) {
    int e = blockIdx.x * 256 + threadIdx.x;
    if (e < E) {
        int r = ei[e];
        int c = ei[E + e];
        atomicAdd(&deg[r], 1.0f);
        atomicAdd(&a[(size_t)r * N + c], 1.0f);
    }
}

__global__ void dinv_k(const float* __restrict__ deg, float* __restrict__ dinv) {
    int i = blockIdx.x * 256 + threadIdx.x;
    if (i < N) {
        float d = deg[i];
        dinv[i] = (d > 0.0f) ? (1.0f / sqrtf(d)) : 0.0f;  // correctly-rounded div+sqrt = numpy
    }
}

// a[i,j] = (i==j ? 1 : 0) - (dinv[i]*A_ij)*dinv[j]   (exact numpy op order)
__global__ void form_L_k(float* __restrict__ a, const float* __restrict__ dinv) {
    unsigned idx = blockIdx.x * 256u + threadIdx.x;
    unsigned i = idx >> 12, j = idx & 4095u;
    float v = a[idx];
    float m = (dinv[i] * v) * dinv[j];
    a[idx] = ((i == j) ? 1.0f : 0.0f) - m;
}

__global__ void init_y_k(const float* __restrict__ x, float* __restrict__ y) {
    int idx = blockIdx.x * 256 + threadIdx.x;
    if (idx < N * CIN) y[idx] = x[idx];
}

// Transpose weights to [i][o] layout for coalesced lane-o access in spectral_k.
__global__ void prepw_k(const float* __restrict__ hh, const float* __restrict__ cw,
                        const float* __restrict__ rw, const float* __restrict__ iw,
                        float2* __restrict__ hcT, float4* __restrict__ rwT,
                        float4* __restrict__ iwT) {
    int idx = blockIdx.x * 256 + threadIdx.x;   // 4096 = i*64+o
    int i = idx >> 6, o = idx & 63;
    int src = o * 64 + i;
    hcT[idx] = make_float2(hh[src], cw[src]);
    rwT[idx] = make_float4(rw[src * 4 + 0], rw[src * 4 + 1], rw[src * 4 + 2], rw[src * 4 + 3]);
    iwT[idx] = make_float4(iw[src * 4 + 0], iw[src * 4 + 1], iw[src * 4 + 2], iw[src * 4 + 3]);
}

// Stage 1: block-level argmax of where(j>i, |a|, 0), first-occurrence (min flat idx) on ties.
__global__ void amax1_k(const float* __restrict__ a, float* __restrict__ pval, int* __restrict__ pidx) {
    int t = threadIdx.x;
    unsigned base = blockIdx.x * 16384u;
    float bv = -1.0f;
    int bi = 0;
    for (int s = 0; s < 64; ++s) {
        unsigned idx = base + (unsigned)s * 256u + t;   // increasing per thread -> strict > keeps first
        unsigned i = idx >> 12, j = idx & 4095u;
        float v = (j > i) ? fabsf(a[idx]) : 0.0f;
        if (v > bv) { bv = v; bi = (int)idx; }
    }
    __shared__ float sv[256];
    __shared__ int si[256];
    sv[t] = bv; si[t] = bi;
    __syncthreads();
    for (int off = 128; off > 0; off >>= 1) {
        if (t < off) {
            float v2 = sv[t + off]; int i2 = si[t + off];
            if (v2 > sv[t] || (v2 == sv[t] && i2 < si[t])) { sv[t] = v2; si[t] = i2; }
        }
        __syncthreads();
    }
    if (t == 0) { pval[blockIdx.x] = sv[0]; pidx[blockIdx.x] = si[0]; }
}

// Fused: final argmax reduce + rotation params + column update + y update + row update.
// Single block of 1024 threads; __syncthreads() between phases gives the
// column-then-row ordering the reference requires.
__global__ void __launch_bounds__(1024) rot_fused_k(
        float* __restrict__ a, float* __restrict__ y,
        const float* __restrict__ pval, const int* __restrict__ pidx,
        int* __restrict__ rotk, int* __restrict__ rotl,
        float* __restrict__ rotc, float* __restrict__ rotsv, int it) {
    int t = threadIdx.x;
    __shared__ float sv[1024];
    __shared__ int si[1024];
    sv[t] = pval[t]; si[t] = pidx[t];
    __syncthreads();
    for (int off = 512; off > 0; off >>= 1) {
        if (t < off) {
            float v2 = sv[t + off]; int i2 = si[t + off];
            if (v2 > sv[t] || (v2 == sv[t] && i2 < si[t])) { sv[t] = v2; si[t] = i2; }
        }
        __syncthreads();
    }
    __shared__ int skk, sll;
    __shared__ float scc, sss;
    if (t == 0) {
        int k = si[0] >> 12;
        int l = si[0] & 4095;
        float akl = a[(size_t)k * N + l];
        float aDiff = a[(size_t)l * N + l] - a[(size_t)k * N + k];
        float akl_safe = (akl == 0.0f) ? 1.0f : akl;
        float aDiff_safe = (aDiff == 0.0f) ? 1.0f : aDiff;
        float phi = aDiff / (2.0f * akl_safe);
        float t2 = 1.0f / (fabsf(phi) + sqrtf(phi * phi + 1.0f));
        t2 = (phi < 0.0f) ? -t2 : t2;
        float t1 = akl / aDiff_safe;
        float tt = (fabsf(akl) < fabsf(aDiff) * 1e-36f) ? t1 : t2;
        float cv = 1.0f / sqrtf(tt * tt + 1.0f);
        float sval = tt * cv;
        rotk[it] = k; rotl[it] = l; rotc[it] = cv; rotsv[it] = sval;
        skk = k; sll = l; scc = cv; sss = sval;
    }
    __syncthreads();
    int k = skk, l = sll;
    float c = scc, s = sss;
    // Phase 2: column update (all rows), plus incremental U^T x on rows k,l of y.
    for (int i = t; i < N; i += 1024) {
        float ck = a[(size_t)i * N + k];
        float cl = a[(size_t)i * N + l];
        a[(size_t)i * N + k] = c * ck - s * cl;
        a[(size_t)i * N + l] = s * ck + c * cl;
    }
    if (t < CIN) {
        float yk = y[k * CIN + t];
        float yl = y[l * CIN + t];
        y[k * CIN + t] = c * yk - s * yl;   // (G^T y)[k]
        y[l * CIN + t] = s * yk + c * yl;   // (G^T y)[l]
    }
    __syncthreads();
    // Phase 3: row update (reads post-column values), then zero a[k,l], a[l,k].
    for (int j = t; j < N; j += 1024) {
        float rk = a[(size_t)k * N + j];
        float rl = a[(size_t)l * N + j];
        float nk = c * rk - s * rl;
        float nl = s * rk + c * rl;
        if (j == l) nk = 0.0f;
        if (j == k) nl = 0.0f;
        a[(size_t)k * N + j] = nk;
        a[(size_t)l * N + j] = nl;
    }
}

// z[n,o] = sum_i g(o,i,n) * y[n,i]; transcendental-free via
// cos(2*atan(1/hw)) = (hw^2-1)/(hw^2+1), sin = 2hw/(hw^2+1), Chebyshev for j=2..4.
// hw<=EPS branch: a2=2 exactly -> start recurrence at (cos2, sin2).
__global__ void __launch_bounds__(1024) spectral_k(
        const float* __restrict__ a, const float* __restrict__ y,
        const float2* __restrict__ hcT, const float4* __restrict__ rwT,
        const float4* __restrict__ iwT, float* __restrict__ z) {
    int o = threadIdx.x & 63;
    int nl = threadIdx.x >> 6;          // 0..15
    int n = blockIdx.x * 16 + nl;
    __shared__ float saux[16][CIN];
    saux[nl][o] = y[n * CIN + o];
    __syncthreads();
    float wn = a[(size_t)n * 4097u];    // diagonal
    const float C2 = -0.41614683654714241f;   // cos(2.0)
    const float S2 = 0.90929742682568170f;    // sin(2.0)
    float acc = 0.0f;
    for (int i = 0; i < CIN; ++i) {
        float2 hc = hcT[i * 64 + o];
        float hw = hc.x * wn;
        float t2v = hw * hw;
        float inv = 1.0f / (t2v + 1.0f);
        float c1 = (t2v - 1.0f) * inv;
        float s1 = (2.0f * hw) * inv;
        if (!(hw > 1e-5f)) { c1 = C2; s1 = S2; }
        float4 rwv = rwT[i * 64 + o];
        float4 iwv = iwT[i * 64 + o];
        float g = hc.y;
        float cj = c1, sj = s1;
        g += rwv.x * cj - iwv.x * sj;
        float cn = cj * c1 - sj * s1; float sn = sj * c1 + cj * s1; cj = cn; sj = sn;
        g += rwv.y * cj - iwv.y * sj;
        cn = cj * c1 - sj * s1; sn = sj * c1 + cj * s1; cj = cn; sj = sn;
        g += rwv.z * cj - iwv.z * sj;
        cn = cj * c1 - sj * s1; sn = sj * c1 + cj * s1; cj = cn; sj = sn;
        g += rwv.w * cj - iwv.w * sj;
        acc += g * saux[nl][i];
    }
    z[(size_t)n * COUT + o] = acc;
}

// output = U @ out.T : apply G_10 ... G_1 to z rows (each thread owns one column).
__global__ void finalrot_k(float* __restrict__ z,
                           const int* __restrict__ rotk, const int* __restrict__ rotl,
                           const float* __restrict__ rotc, const float* __restrict__ rotsv) {
    int col = threadIdx.x;  // 0..63
    for (int i = ITERS - 1; i >= 0; --i) {
        int k = rotk[i], l = rotl[i];
        float c = rotc[i], s = rotsv[i];
        float zk = z[k * COUT + col];
        float zl = z[l * COUT + col];
        z[k * COUT + col] = c * zk + s * zl;   // (G z)[k]
        z[l * COUT + col] = -s * zk + c * zl;  // (G z)[l]
    }
}

__global__ void store_k(const float* __restrict__ z, const float* __restrict__ bias,
                        float* __restrict__ out) {
    int idx = blockIdx.x * 256 + threadIdx.x;
    if (idx < N * COUT) {
        int o = idx & 63;
        out[idx] = z[idx] + bias[o];
    }
}

extern "C" void kernel_launch(void* const* d_in, const int* in_sizes, int n_in,
                              void* d_out, int out_size, void* d_ws, size_t ws_size,
                              hipStream_t stream) {
    const float* x   = (const float*)d_in[0];
    const int*   ei  = (const int*)d_in[1];
    const float* rw  = (const float*)d_in[2];
    const float* iw  = (const float*)d_in[3];
    const float* hh  = (const float*)d_in[4];
    const float* cw  = (const float*)d_in[5];
    const float* bias= (const float*)d_in[6];
    float* out = (float*)d_out;

    // Workspace carve (~69.4 MB total)
    float* a    = (float*)d_ws;             // 16777216 f32 (64 MB)
    float* deg  = a + (size_t)N * N;        // 4096
    float* dinv = deg + N;                  // 4096
    float* y    = dinv + N;                 // 262144 : U^T x (incrementally rotated)
    float* z    = y + N * CIN;              // 262144 : out.T then U*out.T
    float2* hcT = (float2*)(z + N * COUT);  // 4096 float2
    float4* rwT = (float4*)(hcT + 4096);    // 4096 float4
    float4* iwT = rwT + 4096;               // 4096 float4
    float* pval = (float*)(iwT + 4096);     // 1024
    int*   pidx = (int*)(pval + 1024);      // 1024
    int*   rotk = pidx + 1024;              // 16
    int*   rotl = rotk + 16;                // 16
    float* rotc = (float*)(rotl + 16);      // 16
    float* rotsv= rotc + 16;                // 16

    int E = in_sizes[1] / 2;                // 200000 (row half of edge_index)

    // zero a and deg in one memset (contiguous)
    hipMemsetAsync(a, 0, ((size_t)N * N + N) * sizeof(float), stream);

    int eb = (E + 255) / 256;
    edges_k<<<eb, 256, 0, stream>>>(ei, deg, a, E);
    dinv_k<<<16, 256, 0, stream>>>(deg, dinv);
    prepw_k<<<16, 256, 0, stream>>>(hh, cw, rw, iw, hcT, rwT, iwT);
    form_L_k<<<(N * N) / 256, 256, 0, stream>>>(a, dinv);
    init_y_k<<<(N * CIN) / 256, 256, 0, stream>>>(x, y);

    for (int it = 0; it < ITERS; ++it) {
        amax1_k<<<1024, 256, 0, stream>>>(a, pval, pidx);
        rot_fused_k<<<1, 1024, 0, stream>>>(a, y, pval, pidx, rotk, rotl, rotc, rotsv, it);
    }

    spectral_k<<<N / 16, 1024, 0, stream>>>(a, y, hcT, rwT, iwT, z);
    finalrot_k<<<1, 64, 0, stream>>>(z, rotk, rotl, rotc, rotsv);
    store_k<<<(N * COUT) / 256, 256, 0, stream>>>(z, bias, out);
}